// Round 13
// baseline (416.102 us; speedup 1.0000x reference)
//
#include <hip/hip_runtime.h>

// ---------------------------------------------------------------------------
// MultiHeadAttention: B=2, S=2048, E=1024, H=16, D=64, causal. fp32 I/O.
// R13: attn VALU diet + kernel fusion.
//  - Q pre-scaled by (log2e/sqrt(64)) in qkv epilogue -> no per-iter scale mul.
//  - bf16 packing via one v_perm_b32 per 2 values (truncation; P in [0,1],
//    bias cancels in O/l; headroom 0.0039 vs 0.0226).
//  - attn_combine fused into attn_partial: last-arriving chunk block (flag in
//    ws, zeroed by prep, device-scope atomicAdd + threadfence) merges partials.
// Else unchanged from R12 (S^T=K*Q^T register-resident P, GLL dbuf staging).
// ---------------------------------------------------------------------------

typedef __attribute__((ext_vector_type(8))) short short8;
typedef __attribute__((ext_vector_type(4))) short short4v;
typedef __attribute__((ext_vector_type(4))) float floatx4;

#define NB 2
#define SEQ 2048
#define EMB 1024
#define NH 16
#define HD 64
#define M_ROWS (NB * SEQ)        // 4096
#define N_QKV (3 * EMB)          // 3072
#define SLOT_B 8448              // bytes: 64x64 bf16 O (8192) + 64 fp32 l (256)
#define SC_Q 0.18033688011112043f  // (1/sqrt(64)) * log2(e)

#define GLL(g, l) __builtin_amdgcn_global_load_lds( \
    (const __attribute__((address_space(1))) void*)(g), \
    (__attribute__((address_space(3))) void*)(l), 16, 0, 0)

#if defined(__HIP_DEVICE_COMPILE__)
#define MFMA16K16(A, B, C) __builtin_amdgcn_mfma_f32_16x16x16bf16_1k(A, B, C, 0, 0, 0)
#else
#define MFMA16K16(A, B, C) (C)   // host pass parses but never executes this
#endif

static __device__ __forceinline__ unsigned short f2bf(float f) {
    union { float f; unsigned int u; } v; v.f = f;
    unsigned int r = v.u + 0x7FFFu + ((v.u >> 16) & 1u);
    return (unsigned short)(r >> 16);
}
static __device__ __forceinline__ float bf2f(unsigned short h) {
    union { unsigned int u; float f; } v; v.u = ((unsigned int)h) << 16;
    return v.f;
}
// pack hi16(a) into low short, hi16(b) into high short — one v_perm_b32
static __device__ __forceinline__ unsigned int pkhi(float a, float b) {
    union { float f; unsigned int u; } ua, ub; ua.f = a; ub.f = b;
    return __builtin_amdgcn_perm(ub.u, ua.u, 0x07060302u);
}

// Fused prep: z=0 transpose W_qkv, z=1 transpose W_o (+ zero merge flags),
// z=2 convert x -> bf16.
__global__ void prep(const float* __restrict__ x,
                     const float* __restrict__ Wqkv, const float* __restrict__ Wo,
                     unsigned short* __restrict__ x_bf,
                     unsigned short* __restrict__ wqkvT, unsigned short* __restrict__ woT,
                     int* __restrict__ flags) {
    __shared__ unsigned short tile[32][33];
    int z = blockIdx.z;
    int tx = threadIdx.x, ty = threadIdx.y;
    if (z == 2) {
        int id = ((int)blockIdx.y * 96 + (int)blockIdx.x) * 256 + ty * 32 + tx;
        const int n4 = M_ROWS * EMB / 4;
        for (int i = id; i < n4; i += 96 * 32 * 256) {
            float4 v = ((const float4*)x)[i];
            unsigned long long p = (unsigned long long)f2bf(v.x)
                | ((unsigned long long)f2bf(v.y) << 16)
                | ((unsigned long long)f2bf(v.z) << 32)
                | ((unsigned long long)f2bf(v.w) << 48);
            ((unsigned long long*)x_bf)[i] = p;
        }
        return;
    }
    int C = z ? EMB : N_QKV;
    if ((int)blockIdx.x * 32 >= C) return;
    if (z == 1 && blockIdx.x == 0 && blockIdx.y == 0) {
        int id = ty * 32 + tx;
        flags[id] = 0;
        flags[id + 256] = 0;
    }
    const float* in = z ? Wo : Wqkv;
    unsigned short* out = z ? woT : wqkvT;
    const int R = EMB;
    int c0 = blockIdx.x * 32, r0 = blockIdx.y * 32;
    #pragma unroll
    for (int j = 0; j < 4; ++j)
        tile[ty + j * 8][tx] = f2bf(in[(size_t)(r0 + ty + j * 8) * C + c0 + tx]);
    __syncthreads();
    #pragma unroll
    for (int j = 0; j < 4; ++j)
        out[(size_t)(c0 + ty + j * 8) * R + r0 + tx] = tile[tx][ty + j * 8];
}

// ---------------------------------------------------------------------------
// QKV GEMM: single-barrier dbuf GLL K-loop + LDS-roundtrip coalesced epilogue.
// Q (pre-scaled by SC_Q), K -> [B,H,S,D]; V -> [B,H,D,S].
// ---------------------------------------------------------------------------
#define CTS 130   // C-tile LDS stride (shorts), pad 2

__global__ __launch_bounds__(256) void qkv_gemm(
    const unsigned short* __restrict__ A,    // x_bf [4096][1024]
    const unsigned short* __restrict__ Bt,   // W_qkv^T [3072][1024] bf16
    const float* __restrict__ bias,          // [3072] fp32
    unsigned short* __restrict__ qb, unsigned short* __restrict__ kb,
    unsigned short* __restrict__ vb)         // vb: [B,H,D,S]
{
    const int K = EMB;
    __shared__ __align__(16) unsigned short smem[128 * CTS];

    int t = threadIdx.x;
    int m0 = blockIdx.y * 128;
    int n0 = blockIdx.x * 128;
    int w = t >> 6, lane = t & 63, quad = lane >> 4, lcol = lane & 15;
    int wr = w >> 1, wc = w & 1;

    floatx4 zero = {0.f, 0.f, 0.f, 0.f};
    floatx4 acc[4][4];
    #pragma unroll
    for (int i = 0; i < 4; ++i)
        #pragma unroll
        for (int j = 0; j < 4; ++j) acc[i][j] = zero;

    const unsigned short* a0 = A  + (size_t)(m0 + (t >> 2)) * K + ((t & 3) << 3);
    const unsigned short* b0 = Bt + (size_t)(n0 + (t >> 2)) * K + ((t & 3) << 3);
    unsigned short* la = &smem[t << 3];          // + buf*8192 ; Bs at +4096

    GLL(a0, la);
    GLL(a0 + 64 * K, la + 2048);
    GLL(b0, la + 4096);
    GLL(b0 + 64 * K, la + 6144);

    for (int k0 = 0; k0 < K; k0 += 32) {
        int cur = (k0 >> 5) & 1, nxt = cur ^ 1;
        __syncthreads();                         // drains cur's staging loads
        if (k0 + 32 < K) {                       // prefetch nxt AFTER barrier
            GLL(a0 + k0 + 32, la + nxt * 8192);
            GLL(a0 + 64 * K + k0 + 32, la + nxt * 8192 + 2048);
            GLL(b0 + k0 + 32, la + nxt * 8192 + 4096);
            GLL(b0 + 64 * K + k0 + 32, la + nxt * 8192 + 6144);
        }
        const unsigned short* As = &smem[cur * 8192];
        const unsigned short* Bs = As + 4096;
        short8 af[4], bfm[4];
        #pragma unroll
        for (int i = 0; i < 4; ++i)
            af[i] = *(const short8*)(&As[(wr * 64 + i * 16 + lcol) * 32 + quad * 8]);
        #pragma unroll
        for (int j = 0; j < 4; ++j)
            bfm[j] = *(const short8*)(&Bs[(wc * 64 + j * 16 + lcol) * 32 + quad * 8]);
        #pragma unroll
        for (int i = 0; i < 4; ++i)
            #pragma unroll
            for (int j = 0; j < 4; ++j)
                acc[i][j] = __builtin_amdgcn_mfma_f32_16x16x32_bf16(af[i], bfm[j], acc[i][j], 0, 0, 0);
    }

    // ---- epilogue: bias (+Q scale) + bf16 into LDS C-tile, then streams ----
    bool isV = (n0 >= 2 * EMB);
    float scl = (n0 < EMB) ? SC_Q : 1.0f;        // Q third pre-scaled
    __syncthreads();
    #pragma unroll
    for (int i = 0; i < 4; ++i) {
        int row0 = wr * 64 + i * 16 + quad * 4;
        #pragma unroll
        for (int j = 0; j < 4; ++j) {
            int col = wc * 64 + j * 16 + lcol;
            float bv = bias[n0 + col];
            #pragma unroll
            for (int r = 0; r < 4; ++r) {
                unsigned short hv = f2bf((acc[i][j][r] + bv) * scl);
                if (isV) smem[col * CTS + row0 + r] = hv;   // [feature][token]
                else     smem[(row0 + r) * CTS + col] = hv; // [token][feature]
            }
        }
    }
    __syncthreads();

    int b = m0 >> 11, s0 = m0 & 2047;
    int hbase = (n0 & 1023) >> 6;
    if (!isV) {
        unsigned short* dst = (n0 >= EMB) ? kb : qb;
        #pragma unroll
        for (int it = 0; it < 8; ++it) {
            int job = it * 32 + (t >> 3);
            int tok = job & 127, hh = job >> 7;
            int chunk = t & 7;
            short8 vv = *(const short8*)(&smem[tok * CTS + hh * 64 + chunk * 8]);
            size_t g = ((size_t)((b * NH + hbase + hh) * SEQ + s0 + tok)) * HD + chunk * 8;
            *(short8*)(&dst[g]) = vv;
        }
    } else {
        #pragma unroll
        for (int it = 0; it < 8; ++it) {
            int job = it * 32 + (t >> 3);
            int f = job & 127, half = job >> 7;
            int chunk = (t & 7) + half * 8;
            short8 vv = *(const short8*)(&smem[f * CTS + chunk * 8]);
            int h = hbase + (f >> 6), d = f & 63;
            size_t g = ((size_t)((b * NH + h) * HD + d)) * SEQ + s0 + chunk * 8;
            *(short8*)(&vb[g]) = vv;
        }
    }
}

// ---------------------------------------------------------------------------
// Split-K flash attention, causal, fixed softmax base. Block (u, bh):
//   u<16:  qt=u, keys [0, qt+1)           -> final bf16 write
//   u>=16: qt=16+(u-16)/2, c=(u-16)&1     -> partial slot; last arriver merges
// S^T = K*Q^T (C-layout == 16x16x16 B-frag layout) -> PV direct from regs.
// ---------------------------------------------------------------------------
__global__ __launch_bounds__(256) void attn_partial(
    const unsigned short* __restrict__ Q,   // [B*H][S][D], pre-scaled by SC_Q
    const unsigned short* __restrict__ Kk,  // [B*H][S][D]
    const unsigned short* __restrict__ Vt,  // [B*H][D][S]
    unsigned short* __restrict__ Out,       // [b][s][h*64+d]
    unsigned char* __restrict__ Part,       // partial slots (bf16 O + fp32 l)
    int* __restrict__ Flag)                 // [32*16] merge flags (zeroed)
{
    __shared__ __align__(16) unsigned short Ks[2][64 * 64];
    __shared__ __align__(16) unsigned short Vs[2][64 * 64];
    __shared__ int sArr;

    int u = blockIdx.x;              // 0..47
    int bh = blockIdx.y;
    int qt, c;
    if (u < 16) { qt = u; c = 0; }
    else { int v = u - 16; qt = 16 + (v >> 1); c = v & 1; }
    int ktBeg = c << 4;
    int ktEnd = (c == 0 && qt >= 16) ? 16 : (qt + 1);

    int q0 = qt * 64;
    int t = threadIdx.x;
    int w = t >> 6, lane = t & 63, quad = lane >> 4, lcol = lane & 15;
    const size_t hoff = (size_t)bh * SEQ * HD;

    const unsigned short* qp = Q + hoff + (size_t)(q0 + 16 * w + lcol) * HD + quad * 8;
    short8 aq0 = *(const short8*)qp, aq1 = *(const short8*)(qp + 32);

    int srow = t >> 3;                       // 0..31
    int ss   = (t & 7) ^ (srow & 7);
    const unsigned short* kgl = Kk + hoff + (size_t)srow * HD + ss * 8;
    const unsigned short* vgl = Vt + hoff + (size_t)srow * SEQ + ss * 8;
    unsigned short* kld = &Ks[0][t * 8];
    unsigned short* vld = &Vs[0][t * 8];

    floatx4 zero = {0.f, 0.f, 0.f, 0.f};
    floatx4 O[4];                            // O^T: row=d, col=query lcol
    floatx4 lacc = zero;
    #pragma unroll
    for (int d = 0; d < 4; ++d) O[d] = zero;

    short4v ones4;
    #pragma unroll
    for (int j = 0; j < 4; ++j) ones4[j] = (short)0x3F80;  // bf16 1.0

    {   // prologue: stage tile ktBeg into buf 0 (ktBeg is even)
        int k0 = ktBeg * 64;
        GLL(kgl + (size_t)k0 * HD, kld);
        GLL(kgl + (size_t)(k0 + 32) * HD, kld + 2048);
        GLL(vgl + k0, vld);
        GLL(vgl + (size_t)32 * SEQ + k0, vld + 2048);
    }

    int sx0 = (quad ^ (lcol & 7)) << 3;
    int sx1 = sx0 ^ 32;
    int qrow = q0 + 16 * w + lcol;           // this lane's query row

    for (int kt = ktBeg; kt < ktEnd; ++kt) {
        int cur = kt & 1, nxt = cur ^ 1;
        __syncthreads();                     // drains tile-kt staging loads
        if (kt + 1 < ktEnd) {
            int k0 = (kt + 1) * 64;
            GLL(kgl + (size_t)k0 * HD, kld + nxt * 4096);
            GLL(kgl + (size_t)(k0 + 32) * HD, kld + nxt * 4096 + 2048);
            GLL(vgl + k0, vld + nxt * 4096);
            GLL(vgl + (size_t)32 * SEQ + k0, vld + nxt * 4096 + 2048);
        }

        const unsigned short* ksr = &Ks[cur][0];
        const unsigned short* vsr = &Vs[cur][0];
        short8 bk0[4], bk1[4];
        #pragma unroll
        for (int tc = 0; tc < 4; ++tc) {
            int rb = (tc * 16 + lcol) << 6;
            bk0[tc] = *(const short8*)(ksr + rb + sx0);
            bk1[tc] = *(const short8*)(ksr + rb + sx1);
        }
        // V^T A-fragments (independent of S — issued early to overlap exp)
        short4v vaf[4][4];
        #pragma unroll
        for (int td = 0; td < 4; ++td)
            #pragma unroll
            for (int tc = 0; tc < 4; ++tc) {
                int seg = ((tc << 1) + (quad >> 1)) ^ (lcol & 7);
                vaf[td][tc] = *(const short4v*)(vsr + ((td * 16 + lcol) << 6) + (seg << 3) + ((quad & 1) << 2));
            }

        // S^T = K * Q^T (Q pre-scaled: exp2 directly on accumulator)
        floatx4 sacc[4];
        #pragma unroll
        for (int tc = 0; tc < 4; ++tc) {
            sacc[tc] = __builtin_amdgcn_mfma_f32_16x16x32_bf16(bk0[tc], aq0, zero, 0, 0, 0);
            sacc[tc] = __builtin_amdgcn_mfma_f32_16x16x32_bf16(bk1[tc], aq1, sacc[tc], 0, 0, 0);
        }

        // P^T = exp2(S^T), packed bf16 (1 v_perm per 2 vals) -> 16x16x16 B-frag
        bool diag = (kt == qt);
        short4v pk[4];
        #pragma unroll
        for (int tc = 0; tc < 4; ++tc) {
            float pv[4];
            #pragma unroll
            for (int r = 0; r < 4; ++r)
                pv[r] = __builtin_amdgcn_exp2f(sacc[tc][r]);
            if (diag) {
                int kbase = kt * 64 + tc * 16 + quad * 4;
                #pragma unroll
                for (int r = 0; r < 4; ++r)
                    if (kbase + r > qrow) pv[r] = 0.f;
            }
            union { unsigned int u[2]; short4v s; } cv;
            cv.u[0] = pkhi(pv[0], pv[1]);
            cv.u[1] = pkhi(pv[2], pv[3]);
            pk[tc] = cv.s;
        }

        // O^T += V^T * P^T ; l via ones-MFMA
        #pragma unroll
        for (int td = 0; td < 4; ++td)
            #pragma unroll
            for (int tc = 0; tc < 4; ++tc)
                O[td] = MFMA16K16(vaf[td][tc], pk[tc], O[td]);
        #pragma unroll
        for (int tc = 0; tc < 4; ++tc)
            lacc = MFMA16K16(ones4, pk[tc], lacc);
    }

    int b = bh >> 4, h = bh & 15;
    if (qt < 16) {
        float inv = 1.0f / lacc[0];
        size_t obase = ((size_t)b * SEQ + qrow) * EMB + (size_t)h * HD + quad * 4;
        #pragma unroll
        for (int td = 0; td < 4; ++td) {
            union { unsigned int u[2]; short4v s; } cv;
            cv.u[0] = pkhi(O[td][0] * inv, O[td][1] * inv);
            cv.u[1] = pkhi(O[td][2] * inv, O[td][3] * inv);
            *(short4v*)(&Out[obase + td * 16]) = cv.s;
        }
    } else {
        int qh = qt - 16;
        unsigned char* sp = Part + ((size_t)(bh * 16 + qh) * 2 + c) * SLOT_B;
        unsigned short* sO = (unsigned short*)sp;   // [q_local][d]
        float* sL = (float*)(sp + 8192);
        int ql = 16 * w + lcol;
        #pragma unroll
        for (int td = 0; td < 4; ++td) {
            union { unsigned int u[2]; short4v s; } cv;
            cv.u[0] = pkhi(O[td][0], O[td][1]);
            cv.u[1] = pkhi(O[td][2], O[td][3]);
            *(short4v*)(&sO[ql * 64 + td * 16 + quad * 4]) = cv.s;
        }
        if (quad == 0) sL[ql] = lacc[0];

        // ---- last-arriving chunk block merges the two partials ----
        __threadfence();
        if (t == 0) sArr = atomicAdd(&Flag[bh * 16 + qh], 1);
        __syncthreads();
        if (sArr == 1) {
            __threadfence();                 // acquire: see peer's partial
            const unsigned char* s0 = Part + ((size_t)(bh * 16 + qh) * 2) * SLOT_B;
            const unsigned char* s1 = s0 + SLOT_B;
            const unsigned short* O0 = (const unsigned short*)s0;
            const unsigned short* O1 = (const unsigned short*)s1;
            const float* L0 = (const float*)(s0 + 8192);
            const float* L1 = (const float*)(s1 + 8192);
            size_t obase = ((size_t)b * SEQ + qt * 64) * EMB + (size_t)h * HD;
            #pragma unroll
            for (int it = 0; it < 16; ++it) {
                int idx = it * 256 + t;
                int row = idx >> 6, col = idx & 63;
                float lv = L0[row] + L1[row];
                float v = (bf2f(O0[idx]) + bf2f(O1[idx])) / lv;
                Out[obase + (size_t)row * EMB + col] = f2bf(v);
            }
        }
    }
}

// ---------------------------------------------------------------------------
// Output projection: single-barrier dbuf GLL K-loop. fp32 bias, fp32 out.
// ---------------------------------------------------------------------------
__global__ __launch_bounds__(256) void oproj_gemm(
    const unsigned short* __restrict__ A,    // [4096][1024] bf16
    const unsigned short* __restrict__ Bt,   // W_o^T [1024][1024] bf16
    const float* __restrict__ bias,          // [1024] fp32
    float* __restrict__ Cout)                // [4096][1024] fp32
{
    const int K = EMB;
    __shared__ __align__(16) unsigned short smem[2 * 8192];
    int t = threadIdx.x;
    int m0 = blockIdx.y * 128;
    int n0 = blockIdx.x * 128;
    int w = t >> 6, lane = t & 63, quad = lane >> 4, lcol = lane & 15;
    int wr = w >> 1, wc = w & 1;

    floatx4 zero = {0.f, 0.f, 0.f, 0.f};
    floatx4 acc[4][4];
    #pragma unroll
    for (int i = 0; i < 4; ++i)
        #pragma unroll
        for (int j = 0; j < 4; ++j) acc[i][j] = zero;

    const unsigned short* a0 = A  + (size_t)(m0 + (t >> 2)) * K + ((t & 3) << 3);
    const unsigned short* b0 = Bt + (size_t)(n0 + (t >> 2)) * K + ((t & 3) << 3);
    unsigned short* la = &smem[t << 3];

    GLL(a0, la);
    GLL(a0 + 64 * K, la + 2048);
    GLL(b0, la + 4096);
    GLL(b0 + 64 * K, la + 6144);

    for (int k0 = 0; k0 < K; k0 += 32) {
        int cur = (k0 >> 5) & 1, nxt = cur ^ 1;
        __syncthreads();
        if (k0 + 32 < K) {
            GLL(a0 + k0 + 32, la + nxt * 8192);
            GLL(a0 + 64 * K + k0 + 32, la + nxt * 8192 + 2048);
            GLL(b0 + k0 + 32, la + nxt * 8192 + 4096);
            GLL(b0 + 64 * K + k0 + 32, la + nxt * 8192 + 6144);
        }
        const unsigned short* As = &smem[cur * 8192];
        const unsigned short* Bs = As + 4096;
        short8 af[4], bfm[4];
        #pragma unroll
        for (int i = 0; i < 4; ++i)
            af[i] = *(const short8*)(&As[(wr * 64 + i * 16 + lcol) * 32 + quad * 8]);
        #pragma unroll
        for (int j = 0; j < 4; ++j)
            bfm[j] = *(const short8*)(&Bs[(wc * 64 + j * 16 + lcol) * 32 + quad * 8]);
        #pragma unroll
        for (int i = 0; i < 4; ++i)
            #pragma unroll
            for (int j = 0; j < 4; ++j)
                acc[i][j] = __builtin_amdgcn_mfma_f32_16x16x32_bf16(af[i], bfm[j], acc[i][j], 0, 0, 0);
    }

    #pragma unroll
    for (int i = 0; i < 4; ++i) {
        int m = m0 + wr * 64 + i * 16 + quad * 4;
        #pragma unroll
        for (int j = 0; j < 4; ++j) {
            int n = n0 + wc * 64 + j * 16 + lcol;
            float bv = bias[n];
            #pragma unroll
            for (int r = 0; r < 4; ++r)
                Cout[(size_t)(m + r) * EMB + n] = acc[i][j][r] + bv;
        }
    }
}

// ---------------------------------------------------------------------------
extern "C" void kernel_launch(void* const* d_in, const int* in_sizes, int n_in,
                              void* d_out, int out_size, void* d_ws, size_t ws_size,
                              hipStream_t stream) {
    (void)in_sizes; (void)n_in; (void)out_size; (void)ws_size;
    char* ws = (char*)d_ws;
    const size_t OFF_X     = 0;                                      // 8 MB
    const size_t OFF_WQKVT = OFF_X     + (size_t)M_ROWS * EMB * 2;   // 6 MB
    const size_t OFF_WOT   = OFF_WQKVT + (size_t)N_QKV * EMB * 2;    // 2 MB
    const size_t OFF_Q     = OFF_WOT   + (size_t)EMB * EMB * 2;      // 8 MB
    const size_t OFF_K     = OFF_Q     + (size_t)M_ROWS * EMB * 2;   // 8 MB
    const size_t OFF_V     = OFF_K     + (size_t)M_ROWS * EMB * 2;   // 8 MB
    const size_t OFF_ATTN  = OFF_V     + (size_t)M_ROWS * EMB * 2;   // 8 MB
    const size_t OFF_PART  = OFF_ATTN  + (size_t)M_ROWS * EMB * 2;   // ~8.7 MB
    const size_t OFF_FLAG  = OFF_PART  + (size_t)32 * 16 * 2 * SLOT_B;

    const float* x    = (const float*)d_in[0];
    const float* Wqkv = (const float*)d_in[1];
    const float* bqkv = (const float*)d_in[2];
    const float* Wo   = (const float*)d_in[3];
    const float* bo   = (const float*)d_in[4];

    unsigned short* x_bf  = (unsigned short*)(ws + OFF_X);
    unsigned short* wqkvT = (unsigned short*)(ws + OFF_WQKVT);
    unsigned short* woT   = (unsigned short*)(ws + OFF_WOT);
    unsigned short* qb    = (unsigned short*)(ws + OFF_Q);
    unsigned short* kb    = (unsigned short*)(ws + OFF_K);
    unsigned short* vb    = (unsigned short*)(ws + OFF_V);    // [B,H,D,S]
    unsigned short* attn  = (unsigned short*)(ws + OFF_ATTN);
    unsigned char*  part  = (unsigned char*)(ws + OFF_PART);
    int*            flags = (int*)(ws + OFF_FLAG);

    prep<<<dim3(96, 32, 3), dim3(32, 8), 0, stream>>>(x, Wqkv, Wo, x_bf, wqkvT, woT, flags);

    qkv_gemm<<<dim3(N_QKV / 128, M_ROWS / 128), 256, 0, stream>>>(x_bf, wqkvT, bqkv, qb, kb, vb);
    attn_partial<<<dim3(48, NB * NH), 256, 0, stream>>>(qb, kb, vb, attn, part, flags);
    oproj_gemm<<<dim3(EMB / 128, M_ROWS / 128), 256, 0, stream>>>(attn, woT, bo, (float*)d_out);
}